// Round 6
// baseline (270.532 us; speedup 1.0000x reference)
//
#include <hip/hip_runtime.h>

#define BB 16
#define HH 512
#define ROWLEN 1536   // W*C
#define KK 51
#define RR 25

// chunk-level XOR swizzle (involution): spreads strided chunk patterns over
// all 8 bank groups; bijective (only low 3 bits change).
__device__ __forceinline__ int sq(int q) { return q ^ ((q >> 3) & 7); }

// ---------------- K0: reduce 2D kernel to 1D weights (g[i] = row sum) -------
__global__ void k_weights(const float* __restrict__ k2d, float* __restrict__ g) {
    int i = threadIdx.x;
    if (i < KK) {
        float s = 0.f;
        for (int j = 0; j < KK; ++j) s += k2d[i * KK + j];
        g[i] = s;
    }
}

// ---------------- H-pass: 51-tap conv along w, per channel ------------------
// 4 rows/block, 384 threads = 12 (row,channel) planes x 32 lanes; 16 outputs
// per thread. Plane element e = w+28 (pad 28 => 16B-aligned float4 LDS writes
// in both de-interleave and acc write-back). Store addr = plane*576 +
// 4*sq(e>>2) + (e&3). Compute: 18 ds_read_b128/thread; value j (e=16l+j)
// feeds acc[a] with tap tp=j-3-a: 816 FMAs, all compile-time indexed.
// Output re-interleaved through LDS -> 4 coalesced float4 global stores.
#define PSTR 576     // floats per plane = 144 chunks (multiple of 8)
template<bool U8>
__global__ __launch_bounds__(384, 6) void k_hconv(const void* __restrict__ srcv,
                                                  float* __restrict__ dst,
                                                  const float* __restrict__ gsrc) {
    __shared__ __align__(16) float pl[12 * PSTR];
    const int t = threadIdx.x;
    const int row0 = blockIdx.x * 4;             // first of 4 rows (b*512+h)

    float gw[KK];
    #pragma unroll
    for (int i = 0; i < KK; ++i) gw[i] = gsrc[i];   // uniform -> scalar regs

    // ---- load 4 rows, de-interleave into swizzled planes (float4 writes) ---
    #pragma unroll
    for (int it = 0; it < 2; ++it) {
        const int m = t + it * 384;
        if (m < 512) {
            const int r = m >> 7, u = m & 127;       // 12 values = 4 pixels
            const size_t rb = (size_t)(row0 + r) * ROWLEN;
            float f[12];
            if (U8) {
                const unsigned char* s8 = (const unsigned char*)srcv + rb + 12 * u;
                unsigned int ww[3];
                ww[0] = *(const unsigned int*)(s8);
                ww[1] = *(const unsigned int*)(s8 + 4);
                ww[2] = *(const unsigned int*)(s8 + 8);
                #pragma unroll
                for (int k = 0; k < 12; ++k)
                    f[k] = (float)((ww[k >> 2] >> ((k & 3) * 8)) & 0xffu);
            } else {
                const float* sf = (const float*)srcv + rb + 12 * u;
                *(float4*)&f[0] = *(const float4*)(sf);
                *(float4*)&f[4] = *(const float4*)(sf + 4);
                *(float4*)&f[8] = *(const float4*)(sf + 8);
            }
            const int q = 7 + u;                     // chunk of e = 28 + 4u
            #pragma unroll
            for (int c = 0; c < 3; ++c) {
                float4 o;
                o.x = f[c]; o.y = f[3 + c]; o.z = f[6 + c]; o.w = f[9 + c];
                *(float4*)&pl[(r * 3 + c) * PSTR + 4 * sq(q)] = o;
            }
        }
    }
    __syncthreads();

    // ---- reflect halos (np.pad 'reflect'): 12 planes x 50 elements ----
    #pragma unroll
    for (int it = 0; it < 2; ++it) {
        const int item = t + it * 384;
        if (item < 600) {
            const int p = item / 50, k = item % 50;
            int ed, es;
            if (k < 25) { ed = 27 - k;  es = 29 + k; }            // w=-(k+1) <- w=k+1
            else { const int k2 = k - 25; ed = 540 + k2; es = 538 - k2; } // w=512+k2 <- w=510-k2
            float* pb = &pl[p * PSTR];
            pb[4 * sq(ed >> 2) + (ed & 3)] = pb[4 * sq(es >> 2) + (es & 3)];
        }
    }
    __syncthreads();

    // ---- compute: 16 consecutive pixels of one (row,channel) per thread ----
    const int p = t >> 5;             // plane 0..11
    const int l = t & 31;             // lane within plane; w0 = 16*l
    const float* pb = &pl[p * PSTR];
    float acc[16];
    #pragma unroll
    for (int a = 0; a < 16; ++a) acc[a] = 0.f;
    #pragma unroll
    for (int v = 0; v < 18; ++v) {
        const float4 v4 = *(const float4*)&pb[4 * sq(4 * l + v)];
        #pragma unroll
        for (int mm = 0; mm < 4; ++mm) {
            const int j = 4 * v + mm;              // e = 16l + j
            const float val = (&v4.x)[mm];
            #pragma unroll
            for (int a = 0; a < 16; ++a) {
                const int tp = j - 3 - a;          // tap index
                if (tp >= 0 && tp < KK) acc[a] += gw[tp] * val;
            }
        }
    }
    __syncthreads();                  // all reads done before overwrite

    // ---- write acc back into plane (aligned float4, e = 28+16l+k) ----
    {
        const int qb = 7 + 4 * l;
        #pragma unroll
        for (int d = 0; d < 4; ++d) {
            float4 o;
            o.x = acc[4*d]; o.y = acc[4*d+1]; o.z = acc[4*d+2]; o.w = acc[4*d+3];
            *(float4*)&pl[p * PSTR + 4 * sq(qb + d)] = o;
        }
    }
    __syncthreads();

    // ---- re-interleave: 16 flat values per thread -> 4 coalesced float4 ----
    const int r2 = t / 96, s = t % 96;
    const size_t ob = (size_t)(row0 + r2) * ROWLEN + 16 * s;
    float ov[16];
    int c = (16 * s) % 3;
    int w = (16 * s) / 3;
    #pragma unroll
    for (int k = 0; k < 16; ++k) {
        const int e = w + 28;
        ov[k] = pl[(r2 * 3 + c) * PSTR + 4 * sq(e >> 2) + (e & 3)];
        ++c; if (c == 3) { c = 0; ++w; }
    }
    #pragma unroll
    for (int k = 0; k < 4; ++k) {
        float4 o;
        o.x = ov[4*k]; o.y = ov[4*k+1]; o.z = ov[4*k+2]; o.w = ov[4*k+3];
        *(float4*)&dst[ob + 4 * k] = o;
    }
}

// ---------------- V-pass: 51-tap conv along h + fused epilogue --------------
// Tile: 64 flat cols x 128 output rows (+50 halo). 256 threads = 16 col-groups
// (4 cols each, float4) x 16 row-groups (8 rows each): 32 outputs/thread, one
// b128 row-read feeds 4 col-accumulators for up to 8 rows.
// MODE 0: blur -> blurio (d_out as scratch), mask -> mask8.
// MODE 1: soft-mask; read img + blur (from blurio), write final to blurio.
#define FW 64
#define HC 128
#define VROWS 178    // HC + 2*RR

template<int MODE>
__global__ __launch_bounds__(256) void k_vconv(const float* __restrict__ src,
                                               const float* __restrict__ img,
                                               float* blurio,
                                               unsigned char* __restrict__ mask8,
                                               const float* __restrict__ gsrc) {
    __shared__ __align__(16) float tile[VROWS * FW];
    const int t  = threadIdx.x;
    const int cg = t & 15;               // col group: cols 4*cg..4*cg+3
    const int rg = t >> 4;               // row group: rows rg*8..rg*8+7
    const int bid = blockIdx.x;
    const int wcB = bid % 24;
    const int hB  = (bid / 24) & 3;
    const int b   = bid / 96;
    const int wc0 = wcB * 64;
    const int h0  = hB * HC;

    float gw[KK];
    #pragma unroll
    for (int i = 0; i < KK; ++i) gw[i] = gsrc[i];

    const size_t imgbase = (size_t)b * HH * ROWLEN;

    // ---- load tile (178 rows x 16 chunks) with reflect on h ----
    #pragma unroll
    for (int i = 0; i < 12; ++i) {
        const int m = t + 256 * i;
        if (m < VROWS * 16) {
            const int r = m >> 4, cc = m & 15;
            int hs = h0 - RR + r;
            hs = hs < 0 ? -hs : hs;
            hs = hs > 511 ? 1022 - hs : hs;
            *(float4*)&tile[r * FW + 4 * cc] =
                *(const float4*)&src[imgbase + (size_t)hs * ROWLEN + wc0 + 4 * cc];
        }
    }
    __syncthreads();

    float acc[8][4];
    #pragma unroll
    for (int a = 0; a < 8; ++a)
        #pragma unroll
        for (int m = 0; m < 4; ++m) acc[a][m] = 0.f;

    const float* base = &tile[(rg * 8) * FW + 4 * cg];
    #pragma unroll
    for (int jj = 0; jj < 58; ++jj) {
        const float4 v4 = *(const float4*)(base + jj * FW);
        #pragma unroll
        for (int a = 0; a < 8; ++a) {
            const int tap = jj - a;
            if (tap >= 0 && tap < KK) {
                acc[a][0] += gw[tap] * v4.x;
                acc[a][1] += gw[tap] * v4.y;
                acc[a][2] += gw[tap] * v4.z;
                acc[a][3] += gw[tap] * v4.w;
            }
        }
    }

    // ---- fused epilogue ----
    #pragma unroll
    for (int a = 0; a < 8; ++a) {
        const int hh = h0 + rg * 8 + a;
        const size_t idx = imgbase + (size_t)hh * ROWLEN + wc0 + 4 * cg;
        const float4 x4 = *(const float4*)&img[idx];
        if (MODE == 0) {
            float4 bl;
            bl.x = acc[a][0]; bl.y = acc[a][1]; bl.z = acc[a][2]; bl.w = acc[a][3];
            *(float4*)&blurio[idx] = bl;
            unsigned int mw = 0;
            mw |= (fabsf(x4.x - bl.x) * 255.0f > 10.0f) ? 1u : 0u;
            mw |= (fabsf(x4.y - bl.y) * 255.0f > 10.0f) ? (1u << 8) : 0u;
            mw |= (fabsf(x4.z - bl.z) * 255.0f > 10.0f) ? (1u << 16) : 0u;
            mw |= (fabsf(x4.w - bl.w) * 255.0f > 10.0f) ? (1u << 24) : 0u;
            *(unsigned int*)&mask8[idx] = mw;
        } else {
            const float4 bl4 = *(const float4*)&blurio[idx];
            float4 o;
            const float* xp = &x4.x; const float* bp = &bl4.x; float* op = &o.x;
            #pragma unroll
            for (int m = 0; m < 4; ++m) {
                const float x = xp[m];
                const float sharp = fminf(fmaxf(x + 0.5f * (x - bp[m]), 0.f), 1.f);
                op[m] = x + acc[a][m] * (sharp - x);
            }
            *(float4*)&blurio[idx] = o;
        }
    }
}

// ---------------------------------------------------------------------------
extern "C" void kernel_launch(void* const* d_in, const int* in_sizes, int n_in,
                              void* d_out, int out_size, void* d_ws, size_t ws_size,
                              hipStream_t stream) {
    (void)in_sizes; (void)n_in; (void)out_size; (void)ws_size;
    const float* img = (const float*)d_in[0];
    const float* k2d = (const float*)d_in[1];
    float* out = (float*)d_out;

    char* ws = (char*)d_ws;
    float* g = (float*)ws;                                       // 51 floats
    float* tbuf = (float*)(ws + 256);                            // 50.33 MB
    unsigned char* mask8 =
        (unsigned char*)(ws + 256 + (size_t)BB * HH * ROWLEN * 4); // 12.58 MB

    const int nhblk = BB * HH / 4;        // 2048
    const int nvblk = BB * 4 * 24;        // 1536

    k_weights<<<1, 64, 0, stream>>>(k2d, g);
    // P1: H-blur img -> tbuf
    k_hconv<false><<<nhblk, 384, 0, stream>>>((const void*)img, tbuf, g);
    // P2: V-blur tbuf -> blur (into d_out) + mask8
    k_vconv<0><<<nvblk, 256, 0, stream>>>(tbuf, img, out, mask8, g);
    // P3: H-blur mask8 -> tbuf
    k_hconv<true><<<nhblk, 384, 0, stream>>>((const void*)mask8, tbuf, g);
    // P4: V-blur tbuf -> soft mask, fused blend -> d_out
    k_vconv<1><<<nvblk, 256, 0, stream>>>(tbuf, img, out, mask8, g);
}